// Round 3
// baseline (6666.886 us; speedup 1.0000x reference)
//
#include <hip/hip_runtime.h>

// CustomGRU: B=256, T=1024, I=128, H=256.  out = concat(output[B,T,H], h_last[B,H]) f32.
//
// All-f32 pipeline. Phase 2 pairs WGs (2 per batch-pair) with W_hh register-resident;
// cross-WG h exchange via parity-double-buffered packed (version<<32|value) u64 slots
// (agent-scope atomics). Parity buffering makes the protocol deadlock-free: slot[v&1]
// holding version v is only overwritten at v+2, which requires the partner to have
// consumed v first. Spins are bounded so failures surface as wrong answers, not hangs.

#define B_SZ 256
#define T_SZ 1024
#define H_SZ 256
#define G3   768
#define NPAIR 128
#define SPIN_MAX (1 << 28)

static __device__ __forceinline__ size_t xidx(int pair, int role, int parity, int b2, int j) {
    return ((((size_t)pair * 2 + role) * 2 + parity) * 2 + b2) * 128 + j;
}

__device__ __forceinline__ float qadd1(float x) {
    int v = __builtin_amdgcn_update_dpp(0, __float_as_int(x), 0xB1, 0xF, 0xF, true); // quad_perm [1,0,3,2]
    return x + __int_as_float(v);
}
__device__ __forceinline__ float qadd2(float x) {
    int v = __builtin_amdgcn_update_dpp(0, __float_as_int(x), 0x4E, 0xF, 0xF, true); // quad_perm [2,3,0,1]
    return x + __int_as_float(v);
}
__device__ __forceinline__ float qsum(float x) { return qadd2(qadd1(x)); }

// ---------------- prep: exchange slots <- (version 0, h0), both parities ----------------
__global__ void prep_kernel(const float* __restrict__ h0,
                            unsigned long long* __restrict__ xch) {
    int tid = blockIdx.x * blockDim.x + threadIdx.x;
    if (tid < B_SZ * H_SZ) {
        int b = tid >> 8, U = tid & 255;
        int pair = b >> 1, b2 = b & 1, role = U >> 7, j = U & 127;
        unsigned long long val = (unsigned long long)__float_as_uint(h0[tid]);
        xch[xidx(pair, role, 0, b2, j)] = val;   // version 0 (valid for gbase=0 restore)
        xch[xidx(pair, role, 1, b2, j)] = val;   // version 0 never matches an odd want
    }
}

// ---------------- phase 1: gx = x @ W_ih^T, pure f32 ----------------
// grid (B*TC/64, 6), block 256. Block: 64 rho-rows x 128 g-cols, K=128.
__global__ __launch_bounds__(256) void gemm_x_kernel(
    const float* __restrict__ x, const float* __restrict__ wih,
    float* __restrict__ gx, int c, int tcShift)
{
    __shared__ __align__(16) float xs[64 * 128];
    const int TC = 1 << tcShift;
    const int t  = threadIdx.x;
    const int bx = blockIdx.x, by = blockIdx.y;

#pragma unroll
    for (int i = 0; i < 8; ++i) {
        int f4 = t + i * 256;               // 2048 float4s
        int r  = f4 >> 5, c4 = f4 & 31;
        int rho = bx * 64 + r;
        int b = rho >> tcShift, u = rho & (TC - 1);
        float4 v = *(const float4*)(x + ((size_t)b * T_SZ + (size_t)c * TC + u) * 128 + c4 * 4);
        *(float4*)(xs + r * 128 + c4 * 4) = v;
    }
    __syncthreads();

    const int gl = (t & 31) * 4;            // 4 consecutive g-cols
    const int rl = t >> 5;                  // rho_local in {rl, rl+8, ..., rl+56}
    float acc[8][4];
#pragma unroll
    for (int i = 0; i < 8; ++i)
#pragma unroll
        for (int jj = 0; jj < 4; ++jj) acc[i][jj] = 0.f;

    const float* w0 = wih + (size_t)(by * 128 + gl) * 128;
#pragma unroll 4
    for (int k4 = 0; k4 < 32; ++k4) {
        float4 wv[4];
#pragma unroll
        for (int gi = 0; gi < 4; ++gi)
            wv[gi] = *(const float4*)(w0 + (size_t)gi * 128 + k4 * 4);
#pragma unroll
        for (int rr = 0; rr < 8; ++rr) {
            float4 xv = *(const float4*)(xs + (rl + rr * 8) * 128 + k4 * 4);
#pragma unroll
            for (int gi = 0; gi < 4; ++gi) {
                acc[rr][gi] = fmaf(xv.x, wv[gi].x,
                              fmaf(xv.y, wv[gi].y,
                              fmaf(xv.z, wv[gi].z,
                              fmaf(xv.w, wv[gi].w, acc[rr][gi]))));
            }
        }
    }
#pragma unroll
    for (int rr = 0; rr < 8; ++rr) {
        int rho = bx * 64 + rl + rr * 8;
        float4 o; o.x = acc[rr][0]; o.y = acc[rr][1]; o.z = acc[rr][2]; o.w = acc[rr][3];
        *(float4*)(gx + (size_t)rho * G3 + by * 128 + gl) = o;
    }
}

// ---------------- phase 2: paired f32 recurrence ----------------
// 256 WGs x 512 thr. pair = (bid>>4)*8 + (bid&7), role = (bid>>3)&1  (partner = bid^8,
// same XCD under round-robin dispatch). Thread t: wave wv=t>>6, lane l=t&63,
// quad g=l>>2 -> own unit jo = wv*16+g (global ju = ro*128+jo), k-part p=l&3.
// Weights: w[q][i], i in [0,64): k-slice p in i'-space; i<32 own units [32p,32p+32),
// i>=32 partner units [32p,32p+32). 192 f32 VGPRs/thread.
// hl LDS: 4 slices of 132 floats (pad => quad addresses bank-disjoint);
// slice p: [0,64) = own (32 units x 2 batch interleaved), [64,128) = partner.
__global__ __launch_bounds__(512, 2) void gru_kernel(
    const float* __restrict__ gx, const float* __restrict__ whh,
    const float* __restrict__ bih, const float* __restrict__ bhh,
    unsigned long long* __restrict__ xch, float* __restrict__ out,
    int gbase, int tc, int isLast)
{
    __shared__ __align__(16) float hl[4 * 132];

    const int t   = threadIdx.x;
    const int bid = blockIdx.x;
    const int pair = (bid >> 4) * 8 + (bid & 7);
    const int ro   = (bid >> 3) & 1;
    const int roflip = ro << 7;
    const int b0 = pair * 2;

    const int wv = t >> 6, l = t & 63, g = l >> 2, p = l & 3;
    const int jo = wv * 16 + g;            // own-local unit
    const int ju = roflip + jo;            // global unit

    // ---- register-resident weights ----
    float w[192];
    {
        const int kO = roflip + 32 * p;
        const int kP = (roflip ^ 128) + 32 * p;
#pragma unroll
        for (int q = 0; q < 3; ++q) {
            const float* wr = whh + (size_t)(q * 256 + ju) * H_SZ;
#pragma unroll
            for (int v4 = 0; v4 < 8; ++v4) {
                float4 a = *(const float4*)(wr + kO + v4 * 4);
                w[q * 64 + v4 * 4 + 0] = a.x;
                w[q * 64 + v4 * 4 + 1] = a.y;
                w[q * 64 + v4 * 4 + 2] = a.z;
                w[q * 64 + v4 * 4 + 3] = a.w;
                float4 bq = *(const float4*)(wr + kP + v4 * 4);
                w[q * 64 + 32 + v4 * 4 + 0] = bq.x;
                w[q * 64 + 32 + v4 * 4 + 1] = bq.y;
                w[q * 64 + 32 + v4 * 4 + 2] = bq.z;
                w[q * 64 + 32 + v4 * 4 + 3] = bq.w;
            }
        }
    }

    const float bsr = bih[ju]       + bhh[ju];
    const float bsz = bih[256 + ju] + bhh[256 + ju];
    const float bsn = bih[512 + ju] + bhh[512 + ju];

    // ---- restore h(gbase): 512 slots (2 roles x 2 batch x 128 units) ----
    {
        int rr = t >> 8, b2 = (t >> 7) & 1, jj = t & 127;
        unsigned long long* slot = xch + xidx(pair, rr, gbase & 1, b2, jj);
        const unsigned want = (unsigned)gbase;
        unsigned long long v = __hip_atomic_load(slot, __ATOMIC_RELAXED, __HIP_MEMORY_SCOPE_AGENT);
        int spins = 0;
        while ((unsigned)(v >> 32) != want && spins < SPIN_MAX) {
            __builtin_amdgcn_s_sleep(2);
            v = __hip_atomic_load(slot, __ATOMIC_RELAXED, __HIP_MEMORY_SCOPE_AGENT);
            ++spins;
        }
        int pos = (rr == ro)
                ? (jj >> 5) * 132 + (jj & 31) * 2 + b2
                : (jj >> 5) * 132 + (32 + (jj & 31)) * 2 + b2;
        hl[pos] = __uint_as_float((unsigned)v);
    }
    __syncthreads();

    float hold0 = hl[(jo >> 5) * 132 + (jo & 31) * 2 + 0];
    float hold1 = hl[(jo >> 5) * 132 + (jo & 31) * 2 + 1];

    // poller role for threads t<256: one partner slot each
    const int pj = t & 127, pb2 = (t >> 7) & 1;
    const int ppos = (pj >> 5) * 132 + (32 + (pj & 31)) * 2 + pb2;
    const int prole = 1 - ro;

    const float* gr0p = gx + (size_t)b0 * tc * G3 + ju;
    const float* gr1p = gx + (size_t)(b0 + 1) * tc * G3 + ju;
    const float* hb = hl + p * 132;

#define MV_STEP(i2) { \
        float4 hv = *(const float4*)(hb + 4 * (i2)); \
        a00 = fmaf(w[2*(i2)],       hv.x, a00); a01 = fmaf(w[2*(i2)],       hv.y, a01); \
        a00 = fmaf(w[2*(i2)+1],     hv.z, a00); a01 = fmaf(w[2*(i2)+1],     hv.w, a01); \
        a10 = fmaf(w[64+2*(i2)],    hv.x, a10); a11 = fmaf(w[64+2*(i2)],    hv.y, a11); \
        a10 = fmaf(w[64+2*(i2)+1],  hv.z, a10); a11 = fmaf(w[64+2*(i2)+1],  hv.w, a11); \
        a20 = fmaf(w[128+2*(i2)],   hv.x, a20); a21 = fmaf(w[128+2*(i2)],   hv.y, a21); \
        a20 = fmaf(w[128+2*(i2)+1], hv.z, a20); a21 = fmaf(w[128+2*(i2)+1], hv.w, a21); \
    }

    for (int u = 0; u < tc; ++u) {
        // gx loads for this step (issued early; consumed after partner half)
        size_t go = (size_t)u * G3;
        float gxr0 = gr0p[go], gxz0 = gr0p[go + 256], gxn0 = gr0p[go + 512];
        float gxr1 = gr1p[go], gxz1 = gr1p[go + 256], gxn1 = gr1p[go + 512];

        float a00 = 0.f, a01 = 0.f, a10 = 0.f, a11 = 0.f, a20 = 0.f, a21 = 0.f;
        // -- own half (h available from previous step) --
#pragma unroll
        for (int i2 = 0; i2 < 16; ++i2) MV_STEP(i2)

        // -- fetch partner half h(gbase+u) (u=0 came from restore) --
        if (u > 0 && t < 256) {
            const unsigned want = (unsigned)(gbase + u);
            unsigned long long* slot = xch + xidx(pair, prole, (gbase + u) & 1, pb2, pj);
            unsigned long long v = __hip_atomic_load(slot, __ATOMIC_RELAXED, __HIP_MEMORY_SCOPE_AGENT);
            int spins = 0;
            while ((unsigned)(v >> 32) != want && spins < SPIN_MAX) {
                __builtin_amdgcn_s_sleep(2);
                v = __hip_atomic_load(slot, __ATOMIC_RELAXED, __HIP_MEMORY_SCOPE_AGENT);
                ++spins;
            }
            hl[ppos] = __uint_as_float((unsigned)v);
        }
        __syncthreads();

        // -- partner half --
#pragma unroll
        for (int i2 = 16; i2 < 32; ++i2) MV_STEP(i2)

        // -- quad reduce (pure-VALU DPP butterfly; all 4 lanes get the sum) --
        float s00 = qsum(a00), s01 = qsum(a01);
        float s10 = qsum(a10), s11 = qsum(a11);
        float s20 = qsum(a20), s21 = qsum(a21);

        // -- gates (all lanes redundantly; bit-identical across the quad) --
        float ar0 = s00 + gxr0 + bsr, ar1 = s01 + gxr1 + bsr;
        float az0 = s10 + gxz0 + bsz, az1 = s11 + gxz1 + bsz;
        float an0 = s20 + gxn0 + bsn, an1 = s21 + gxn1 + bsn;
        float r0 = 1.f / (1.f + expf(-ar0));
        float r1 = 1.f / (1.f + expf(-ar1));
        float z0 = 1.f / (1.f + expf(-az0));
        float z1 = 1.f / (1.f + expf(-az1));
        float n0 = tanhf(r0 * an0);
        float n1 = tanhf(r1 * an1);
        float hn0 = (1.f - z0) * hold0 + z0 * n0;
        float hn1 = (1.f - z1) * hold1 + z1 * n1;
        hold0 = hn0; hold1 = hn1;

        const int tg = gbase + u;
        if (p == 0) {
            // next-step own h into LDS (safe: all stage-1 reads done before the
            // barrier above; concurrent stage-4 reads touch partner region only)
            hl[(jo >> 5) * 132 + (jo & 31) * 2 + 0] = hn0;
            hl[(jo >> 5) * 132 + (jo & 31) * 2 + 1] = hn1;
            size_t o0 = ((size_t)b0 * T_SZ + tg) * H_SZ + ju;
            out[o0] = hn0;
            out[o0 + (size_t)T_SZ * H_SZ] = hn1;
            if (isLast && u == tc - 1) {
                out[(size_t)B_SZ * T_SZ * H_SZ + (size_t)b0 * H_SZ + ju]       = hn0;
                out[(size_t)B_SZ * T_SZ * H_SZ + (size_t)(b0 + 1) * H_SZ + ju] = hn1;
            }
            const unsigned long long ver = (unsigned long long)(unsigned)(tg + 1) << 32;
            const int par = (tg + 1) & 1;
            __hip_atomic_store(xch + xidx(pair, ro, par, 0, jo),
                               ver | (unsigned long long)__float_as_uint(hn0),
                               __ATOMIC_RELAXED, __HIP_MEMORY_SCOPE_AGENT);
            __hip_atomic_store(xch + xidx(pair, ro, par, 1, jo),
                               ver | (unsigned long long)__float_as_uint(hn1),
                               __ATOMIC_RELAXED, __HIP_MEMORY_SCOPE_AGENT);
        }
        __syncthreads();
    }
#undef MV_STEP
}

// ---------------- host ----------------
extern "C" void kernel_launch(void* const* d_in, const int* in_sizes, int n_in,
                              void* d_out, int out_size, void* d_ws, size_t ws_size,
                              hipStream_t stream) {
    const float* x   = (const float*)d_in[0];
    const float* h0  = (const float*)d_in[1];
    const float* wih = (const float*)d_in[2];
    const float* whh = (const float*)d_in[3];
    const float* bih = (const float*)d_in[4];
    const float* bhh = (const float*)d_in[5];
    float* out = (float*)d_out;

    char* ws = (char*)d_ws;
    const size_t xchB = (size_t)NPAIR * 2 * 2 * 2 * 128 * 8;   // 1 MiB
    unsigned long long* xch = (unsigned long long*)ws;
    float* gxb = (float*)(ws + xchB);

    int tcShift = 10;
    while (tcShift > 0 &&
           xchB + ((size_t)G3 * 4 * B_SZ << tcShift) > ws_size) --tcShift;
    const int TC  = 1 << tcShift;
    const int nCh = T_SZ / TC;

    prep_kernel<<<dim3(256), dim3(256), 0, stream>>>(h0, xch);
    for (int c = 0; c < nCh; ++c) {
        gemm_x_kernel<<<dim3(B_SZ * TC / 64, 6), dim3(256), 0, stream>>>(
            x, wih, gxb, c, tcShift);
        gru_kernel<<<dim3(B_SZ), dim3(512), 0, stream>>>(
            gxb, whh, bih, bhh, xch, out, c * TC, TC, (c == nCh - 1) ? 1 : 0);
    }
}